// Round 1
// baseline (400.033 us; speedup 1.0000x reference)
//
#include <hip/hip_runtime.h>
#include <climits>

#define N_MASKS 64
#define H 1024
#define W 1024
#define ROWS_PER_BLOCK 8
#define THREADS 256

__device__ __forceinline__ int imin(int a, int b) { return a < b ? a : b; }
__device__ __forceinline__ int imax(int a, int b) { return a > b ? a : b; }

// ws layout per mask i: [i*5+0]=cmin, [i*5+1]=rmin, [i*5+2]=cmax, [i*5+3]=rmax, [i*5+4]=count
__global__ void fastsam_init_ws(int* __restrict__ ws) {
    int i = threadIdx.x;
    if (i < N_MASKS) {
        ws[i * 5 + 0] = INT_MAX;
        ws[i * 5 + 1] = INT_MAX;
        ws[i * 5 + 2] = -1;
        ws[i * 5 + 3] = -1;
        ws[i * 5 + 4] = 0;
    }
}

__global__ __launch_bounds__(THREADS) void fastsam_mask_reduce(
    const float* __restrict__ masks, int* __restrict__ ws) {
    const int mask = blockIdx.y;
    const int r0 = blockIdx.x * ROWS_PER_BLOCK;
    const int t = threadIdx.x;

    const float4* base =
        (const float4*)(masks + (size_t)mask * H * W);
    const int col = t * 4;  // thread t covers cols [4t, 4t+3] of each row

    int cmin = INT_MAX, rmin = INT_MAX, cmax = -1, rmax = -1, cnt = 0;

#pragma unroll
    for (int i = 0; i < ROWS_PER_BLOCK; ++i) {
        const int row = r0 + i;
        float4 v = base[row * (W / 4) + t];
        bool a0 = (v.x == 1.0f);
        bool a1 = (v.y == 1.0f);
        bool a2 = (v.z == 1.0f);
        bool a3 = (v.w == 1.0f);
        cnt += (int)a0 + (int)a1 + (int)a2 + (int)a3;
        if (a0 | a1 | a2 | a3) {
            rmin = imin(rmin, row);
            rmax = imax(rmax, row);
            // first / last active column within this float4
            int lo = a0 ? col : (a1 ? col + 1 : (a2 ? col + 2 : col + 3));
            int hi = a3 ? col + 3 : (a2 ? col + 2 : (a1 ? col + 1 : col));
            cmin = imin(cmin, lo);
            cmax = imax(cmax, hi);
        }
    }

    // wave-64 butterfly reduce
#pragma unroll
    for (int off = 32; off > 0; off >>= 1) {
        cmin = imin(cmin, __shfl_down(cmin, off));
        rmin = imin(rmin, __shfl_down(rmin, off));
        cmax = imax(cmax, __shfl_down(cmax, off));
        rmax = imax(rmax, __shfl_down(rmax, off));
        cnt += __shfl_down(cnt, off);
    }

    __shared__ int s[4][5];
    const int wave = t >> 6;
    const int lane = t & 63;
    if (lane == 0) {
        s[wave][0] = cmin;
        s[wave][1] = rmin;
        s[wave][2] = cmax;
        s[wave][3] = rmax;
        s[wave][4] = cnt;
    }
    __syncthreads();
    if (t == 0) {
#pragma unroll
        for (int wv = 1; wv < 4; ++wv) {
            cmin = imin(cmin, s[wv][0]);
            rmin = imin(rmin, s[wv][1]);
            cmax = imax(cmax, s[wv][2]);
            rmax = imax(rmax, s[wv][3]);
            cnt += s[wv][4];
        }
        atomicMin(&ws[mask * 5 + 0], cmin);
        atomicMin(&ws[mask * 5 + 1], rmin);
        atomicMax(&ws[mask * 5 + 2], cmax);
        atomicMax(&ws[mask * 5 + 3], rmax);
        atomicAdd(&ws[mask * 5 + 4], cnt);
    }
}

__global__ void fastsam_finalize(const int* __restrict__ ws,
                                 float* __restrict__ out) {
    int i = threadIdx.x;
    if (i < N_MASKS) {
        // area_thresh = (1024/32)*(1024/32) = 1024; sum of binary mask == count
        bool keep = ws[i * 5 + 4] > 1024;
        out[i * 4 + 0] = keep ? (float)ws[i * 5 + 0] : 0.0f;  // x1 = col min
        out[i * 4 + 1] = keep ? (float)ws[i * 5 + 1] : 0.0f;  // y1 = row min
        out[i * 4 + 2] = keep ? (float)ws[i * 5 + 2] : 0.0f;  // x2 = col max
        out[i * 4 + 3] = keep ? (float)ws[i * 5 + 3] : 0.0f;  // y2 = row max
    }
}

extern "C" void kernel_launch(void* const* d_in, const int* in_sizes, int n_in,
                              void* d_out, int out_size, void* d_ws, size_t ws_size,
                              hipStream_t stream) {
    const float* masks = (const float*)d_in[0];
    float* out = (float*)d_out;
    int* ws = (int*)d_ws;

    fastsam_init_ws<<<1, 64, 0, stream>>>(ws);

    dim3 grid(H / ROWS_PER_BLOCK, N_MASKS);  // 128 x 64 = 8192 blocks
    fastsam_mask_reduce<<<grid, THREADS, 0, stream>>>(masks, ws);

    fastsam_finalize<<<1, 64, 0, stream>>>(ws, out);
}

// Round 2
// 351.859 us; speedup vs baseline: 1.1369x; 1.1369x over previous
//
#include <hip/hip_runtime.h>
#include <climits>

#define N_MASKS 64
#define H 1024
#define W 1024
#define ROWS_PER_BLOCK 8
#define BLOCKS_PER_MASK (H / ROWS_PER_BLOCK)  // 128
#define THREADS 256

__device__ __forceinline__ int imin(int a, int b) { return a < b ? a : b; }
__device__ __forceinline__ int imax(int a, int b) { return a > b ? a : b; }

// Phase 1: one block per (mask, 8-row slab). Block-reduces {cmin,rmin,cmax,rmax,cnt}
// and writes a 5-int partial to its own ws slot. No atomics, no init kernel
// (every slot is unconditionally written each launch, so 0xAA poison is harmless).
__global__ __launch_bounds__(THREADS) void fastsam_partial(
    const float* __restrict__ masks, int* __restrict__ ws) {
    const int mask = blockIdx.y;
    const int bx = blockIdx.x;
    const int r0 = bx * ROWS_PER_BLOCK;
    const int t = threadIdx.x;

    const float4* base = (const float4*)(masks + (size_t)mask * H * W);
    const int col = t * 4;  // thread t covers cols [4t, 4t+3] of every row

    int cmin = INT_MAX, rmin = INT_MAX, cmax = -1, rmax = -1, cnt = 0;

#pragma unroll
    for (int i = 0; i < ROWS_PER_BLOCK; ++i) {
        const int row = r0 + i;
        float4 v = base[row * (W / 4) + t];
        bool a0 = (v.x == 1.0f);
        bool a1 = (v.y == 1.0f);
        bool a2 = (v.z == 1.0f);
        bool a3 = (v.w == 1.0f);
        cnt += (int)a0 + (int)a1 + (int)a2 + (int)a3;
        if (a0 | a1 | a2 | a3) {
            rmin = imin(rmin, row);
            rmax = imax(rmax, row);
            int lo = a0 ? col : (a1 ? col + 1 : (a2 ? col + 2 : col + 3));
            int hi = a3 ? col + 3 : (a2 ? col + 2 : (a1 ? col + 1 : col));
            cmin = imin(cmin, lo);
            cmax = imax(cmax, hi);
        }
    }

    // wave-64 butterfly reduce
#pragma unroll
    for (int off = 32; off > 0; off >>= 1) {
        cmin = imin(cmin, __shfl_down(cmin, off));
        rmin = imin(rmin, __shfl_down(rmin, off));
        cmax = imax(cmax, __shfl_down(cmax, off));
        rmax = imax(rmax, __shfl_down(rmax, off));
        cnt += __shfl_down(cnt, off);
    }

    __shared__ int s[4][5];
    const int wave = t >> 6;
    const int lane = t & 63;
    if (lane == 0) {
        s[wave][0] = cmin;
        s[wave][1] = rmin;
        s[wave][2] = cmax;
        s[wave][3] = rmax;
        s[wave][4] = cnt;
    }
    __syncthreads();
    if (t == 0) {
#pragma unroll
        for (int wv = 1; wv < 4; ++wv) {
            cmin = imin(cmin, s[wv][0]);
            rmin = imin(rmin, s[wv][1]);
            cmax = imax(cmax, s[wv][2]);
            rmax = imax(rmax, s[wv][3]);
            cnt += s[wv][4];
        }
        int* p = ws + (size_t)(mask * BLOCKS_PER_MASK + bx) * 5;
        p[0] = cmin;
        p[1] = rmin;
        p[2] = cmax;
        p[3] = rmax;
        p[4] = cnt;
    }
}

// Phase 2: one block per mask; 128 threads each grab one partial, block-reduce,
// apply the area test, write the 4-float bbox.
__global__ __launch_bounds__(BLOCKS_PER_MASK) void fastsam_final(
    const int* __restrict__ ws, float* __restrict__ out) {
    const int mask = blockIdx.x;
    const int j = threadIdx.x;

    const int* p = ws + (size_t)(mask * BLOCKS_PER_MASK + j) * 5;
    int cmin = p[0], rmin = p[1], cmax = p[2], rmax = p[3], cnt = p[4];

#pragma unroll
    for (int off = 32; off > 0; off >>= 1) {
        cmin = imin(cmin, __shfl_down(cmin, off));
        rmin = imin(rmin, __shfl_down(rmin, off));
        cmax = imax(cmax, __shfl_down(cmax, off));
        rmax = imax(rmax, __shfl_down(rmax, off));
        cnt += __shfl_down(cnt, off);
    }

    __shared__ int s[5];
    const int wave = j >> 6;
    const int lane = j & 63;
    if (wave == 1 && lane == 0) {
        s[0] = cmin;
        s[1] = rmin;
        s[2] = cmax;
        s[3] = rmax;
        s[4] = cnt;
    }
    __syncthreads();
    if (j == 0) {
        cmin = imin(cmin, s[0]);
        rmin = imin(rmin, s[1]);
        cmax = imax(cmax, s[2]);
        rmax = imax(rmax, s[3]);
        cnt += s[4];
        // area_thresh = (1024/32)*(1024/32) = 1024; binary mask => sum == count
        bool keep = cnt > 1024;
        out[mask * 4 + 0] = keep ? (float)cmin : 0.0f;  // x1
        out[mask * 4 + 1] = keep ? (float)rmin : 0.0f;  // y1
        out[mask * 4 + 2] = keep ? (float)cmax : 0.0f;  // x2
        out[mask * 4 + 3] = keep ? (float)rmax : 0.0f;  // y2
    }
}

extern "C" void kernel_launch(void* const* d_in, const int* in_sizes, int n_in,
                              void* d_out, int out_size, void* d_ws, size_t ws_size,
                              hipStream_t stream) {
    const float* masks = (const float*)d_in[0];
    float* out = (float*)d_out;
    int* ws = (int*)d_ws;

    dim3 grid(BLOCKS_PER_MASK, N_MASKS);  // 128 x 64 = 8192 blocks
    fastsam_partial<<<grid, THREADS, 0, stream>>>(masks, ws);
    fastsam_final<<<N_MASKS, BLOCKS_PER_MASK, 0, stream>>>(ws, out);
}